// Round 4
// baseline (1087.925 us; speedup 1.0000x reference)
//
#include <hip/hip_runtime.h>
#include <cmath>

// Problem dims (fixed by setup_inputs)
#define B_SZ  32
#define LATD  64
#define HU    96
#define G4    384
#define T_LEN 512
#define VOC   10000
#define NROWS (B_SZ * T_LEN)        // 16384
#define NC16  625                   // 10000/16 exactly
#define NSPLIT 5
#define C16S  125                   // c16 tiles per split
#define RBLK  32                    // rows per dense block
#define PPR   (NSPLIT * 2)          // partials per row

typedef __attribute__((ext_vector_type(8))) short bf16x8;
typedef __attribute__((ext_vector_type(4))) float f32x4;

__device__ __forceinline__ unsigned short f2bf(float x) {
  unsigned u = __float_as_uint(x);
  u += 0x7fffu + ((u >> 16) & 1u);   // RNE
  return (unsigned short)(u >> 16);
}
__device__ __forceinline__ float fsig(float x) {
  return __builtin_amdgcn_rcpf(1.f + __expf(-x));
}
__device__ __forceinline__ float ftanh(float x) {
  return 1.f - 2.f * __builtin_amdgcn_rcpf(1.f + __expf(2.f * x));
}

// ---------------- Kernel 0: pack Wd into bf16 MFMA-B-fragment order ----------
// Lane chunk for (c16,K16,l): element j = Wd[K16*32+(l>>4)*8+j][c16*16+(l&15)]
__global__ __launch_bounds__(256) void pack_wd(const float* __restrict__ Wd,
                                               uint4* __restrict__ Bp) {
  const int gid = blockIdx.x * 256 + threadIdx.x;
  if (gid >= NC16 * 3 * 64) return;
  const int l   = gid & 63;
  const int K16 = (gid >> 6) % 3;
  const int c16 = gid / 192;
  const int col = c16 * 16 + (l & 15);
  const int k0  = K16 * 32 + (l >> 4) * 8;
  unsigned w[4];
#pragma unroll
  for (int jj = 0; jj < 4; ++jj) {
    float x0 = Wd[(size_t)(k0 + 2 * jj) * VOC + col];
    float x1 = Wd[(size_t)(k0 + 2 * jj + 1) * VOC + col];
    w[jj] = (unsigned)f2bf(x0) | ((unsigned)f2bf(x1) << 16);
  }
  Bp[gid] = make_uint4(w[0], w[1], w[2], w[3]);
}

// ---------------- Kernel 1: LSTM recurrence, 1 wave = 1 batch element -------
// Replicated-A MFMA: A-fragment holds h broadcast to all 16 rows, B = U
// fragments (24 col-tiles x 3 K-tiles, 288 VGPRs). D rows are identical, so
// lane l&15=c holds gates for cols {16t+c}; unit u=c+16m has all 4 gates
// (tiles m, 6+m, 12+m, 18+m) in-lane -> no cross-lane gate exchange at all.
// Single wave: one cheap __syncthreads per step orders the h LDS round trip.
__global__ __launch_bounds__(64, 1) void lstm_wave(
    const float* __restrict__ z, const float* __restrict__ W,
    const float* __restrict__ U, const float* __restrict__ bias,
    unsigned short* __restrict__ hsb) {
  __shared__ __align__(16) unsigned short hbuf[HU];  // 96 bf16 = 192 B
  const int l  = threadIdx.x;
  const int bb = blockIdx.x;
  const int c  = l & 15;      // column class
  const int kg = l >> 4;      // k-group 0..3
  const int k0 = kg * 8;

  if (l < HU / 2) ((unsigned*)hbuf)[l] = 0u;

  // ---- one-time: U as MFMA B-fragments (bf16 pairs packed over k) ----
  bf16x8 Ufr[24][3];
#pragma unroll
  for (int t = 0; t < 24; ++t) {
    const int col = t * 16 + c;
#pragma unroll
    for (int kt = 0; kt < 3; ++kt) {
      const int kb = kt * 32 + k0;
      unsigned w[4];
#pragma unroll
      for (int jj = 0; jj < 4; ++jj) {
        float x0 = U[(size_t)(kb + 2 * jj) * G4 + col];
        float x1 = U[(size_t)(kb + 2 * jj + 1) * G4 + col];
        w[jj] = (unsigned)f2bf(x0) | ((unsigned)f2bf(x1) << 16);
      }
      uint4 u4 = make_uint4(w[0], w[1], w[2], w[3]);
      Ufr[t][kt] = __builtin_bit_cast(bf16x8, u4);
    }
  }

  // ---- one-time: zp = bias + z.W for this lane's 24 columns ----
  float zp[24];
#pragma unroll
  for (int t = 0; t < 24; ++t) zp[t] = bias[t * 16 + c];
  for (int k = 0; k < LATD; ++k) {
    const float zk = z[bb * LATD + k];
    const float* wr = W + (size_t)k * G4 + c;
#pragma unroll
    for (int t = 0; t < 24; ++t) zp[t] = fmaf(zk, wr[t * 16], zp[t]);
  }

  float cst[6];
#pragma unroll
  for (int m = 0; m < 6; ++m) cst[m] = 0.f;

  __syncthreads();

  unsigned short* hrow = hsb + (size_t)bb * T_LEN * HU;

  for (int s = 0; s < T_LEN; ++s) {
    // A fragments: h chunk per k-group (rows replicated)
    bf16x8 afr[3];
#pragma unroll
    for (int kt = 0; kt < 3; ++kt)
      afr[kt] = *(const bf16x8*)(hbuf + kt * 32 + k0);

    float gate[24];
    const f32x4 zero4 = {0.f, 0.f, 0.f, 0.f};
#pragma unroll
    for (int t = 0; t < 24; ++t) {
      f32x4 d = __builtin_amdgcn_mfma_f32_16x16x32_bf16(afr[0], Ufr[t][0], zero4, 0, 0, 0);
      d = __builtin_amdgcn_mfma_f32_16x16x32_bf16(afr[1], Ufr[t][1], d, 0, 0, 0);
      d = __builtin_amdgcn_mfma_f32_16x16x32_bf16(afr[2], Ufr[t][2], d, 0, 0, 0);
      gate[t] = d[0] + zp[t];
    }

    // activations for units u = c + 16m (redundant across the 4 k-groups)
    unsigned short hb16[6];
#pragma unroll
    for (int m = 0; m < 6; ++m) {
      const float i_ = fsig(gate[m]);
      const float f_ = fsig(gate[6 + m]);
      const float cb = ftanh(gate[12 + m]);
      const float o_ = fsig(gate[18 + m]);
      cst[m] = f_ * cst[m] + i_ * cb;
      const float h = o_ * ftanh(cst[m]);
      hb16[m] = f2bf(h);
    }
    if (kg == 0) {
#pragma unroll
      for (int m = 0; m < 6; ++m) hbuf[c + 16 * m] = hb16[m];
    }
    __syncthreads();
    // copy h row to global (12 lanes x 16 B, coalesced)
    if (l < 12) {
      const uint4 hv = *(const uint4*)(hbuf + l * 8);
      *(uint4*)(hrow + (size_t)s * HU + l * 8) = hv;
    }
  }
}

// ---------------- Kernels 2/4: dense GEMM passes ----------------------------
// Grid: 512 row-blocks x NSPLIT v-splits (bid: s=bid/512, rb=bid%512).
// 4 waves: r16 = wv&1 (16-row tile), cg = wv>>1 (odd/even c16 within split).
// PASS 0: partial sum(exp(logit)) -> part[row][s*2+cg].
// PASS 1: recompute logits (identical MFMA sequence) -> nontemporal out.
template <int PASS>
__global__ __launch_bounds__(256) void dense_pass(
    const unsigned short* __restrict__ hsb, const bf16x8* __restrict__ Bp,
    const float* __restrict__ bd, const float* __restrict__ invS,
    float* __restrict__ outp) {
  __shared__ __align__(16) unsigned short Al[RBLK * HU];  // 6 KB
  const int tid = threadIdx.x;
  const int l = tid & 63, wv = tid >> 6;
  const int r16 = wv & 1, cg = wv >> 1;
  const int l15 = l & 15, l4 = l >> 4;
  const int s = blockIdx.x / 512, rb = blockIdx.x % 512;
  const int R0 = rb * RBLK;

  {
    const uint4* src = (const uint4*)(hsb + (size_t)R0 * HU);
    uint4* dst = (uint4*)Al;
    for (int i = tid; i < RBLK * HU / 8; i += 256) dst[i] = src[i];
  }
  __syncthreads();

  bf16x8 afr[3];
#pragma unroll
  for (int K16 = 0; K16 < 3; ++K16)
    afr[K16] = *(const bf16x8*)(Al + (r16 * 16 + l15) * HU + K16 * 32 + l4 * 8);

  float iv[4];
  float ssum[4] = {0.f, 0.f, 0.f, 0.f};
  if (PASS == 1) {
#pragma unroll
    for (int q = 0; q < 4; ++q) iv[q] = invS[R0 + r16 * 16 + l4 * 4 + q];
  }

  const int cbase = s * C16S;
  for (int i = cg; i < C16S; i += 2) {
    const int c16 = cbase + i;
    const bf16x8* bp = Bp + (size_t)c16 * 192 + l;
    const bf16x8 b0 = bp[0], b1 = bp[64], b2 = bp[128];
    f32x4 acc = {0.f, 0.f, 0.f, 0.f};
    acc = __builtin_amdgcn_mfma_f32_16x16x32_bf16(afr[0], b0, acc, 0, 0, 0);
    acc = __builtin_amdgcn_mfma_f32_16x16x32_bf16(afr[1], b1, acc, 0, 0, 0);
    acc = __builtin_amdgcn_mfma_f32_16x16x32_bf16(afr[2], b2, acc, 0, 0, 0);
    const int col = c16 * 16 + l15;
    const float bdv = bd[col];
    if (PASS == 0) {
#pragma unroll
      for (int q = 0; q < 4; ++q) ssum[q] += __expf(acc[q] + bdv);
    } else {
#pragma unroll
      for (int q = 0; q < 4; ++q) {
        const size_t r = (size_t)(R0 + r16 * 16 + l4 * 4 + q);
        __builtin_nontemporal_store(__expf(acc[q] + bdv) * iv[q],
                                    outp + r * VOC + col);
      }
    }
  }

  if (PASS == 0) {
#pragma unroll
    for (int q = 0; q < 4; ++q) {
      float v = ssum[q];
      v += __shfl_xor(v, 1);
      v += __shfl_xor(v, 2);
      v += __shfl_xor(v, 4);
      v += __shfl_xor(v, 8);
      ssum[q] = v;
    }
    if (l15 == 0) {
#pragma unroll
      for (int q = 0; q < 4; ++q)
        outp[(size_t)(R0 + r16 * 16 + l4 * 4 + q) * PPR + s * 2 + cg] = ssum[q];
    }
  }
}

// ---------------- Kernel 3: reduce partials -> invS -------------------------
__global__ __launch_bounds__(256) void reduce_inv(const float* __restrict__ part,
                                                  float* __restrict__ invS) {
  const int r = blockIdx.x * 256 + threadIdx.x;
  if (r < NROWS) {
    float s = 0.f;
#pragma unroll
    for (int i = 0; i < PPR; ++i) s += part[(size_t)r * PPR + i];
    invS[r] = 1.f / s;
  }
}

extern "C" void kernel_launch(void* const* d_in, const int* in_sizes, int n_in,
                              void* d_out, int out_size, void* d_ws, size_t ws_size,
                              hipStream_t stream) {
  const float* z  = (const float*)d_in[0];
  const float* W  = (const float*)d_in[1];
  const float* U  = (const float*)d_in[2];
  const float* b  = (const float*)d_in[3];
  const float* Wd = (const float*)d_in[4];
  const float* bd = (const float*)d_in[5];
  float* out = (float*)d_out;

  char* ws = (char*)d_ws;
  unsigned short* hsb = (unsigned short*)ws;                 // 3,145,728 B
  uint4* Bp   = (uint4*)(ws + 3145728);                      // 1,920,000 B
  float* part = (float*)(ws + 3145728 + 1920000);            //   655,360 B
  float* invS = (float*)(ws + 3145728 + 1920000 + 655360);   //    65,536 B

  pack_wd<<<(NC16 * 3 * 64 + 255) / 256, 256, 0, stream>>>(Wd, Bp);
  lstm_wave<<<B_SZ, 64, 0, stream>>>(z, W, U, b, hsb);
  dense_pass<0><<<512 * NSPLIT, 256, 0, stream>>>(hsb, (const bf16x8*)Bp, bd,
                                                  nullptr, part);
  reduce_inv<<<(NROWS + 255) / 256, 256, 0, stream>>>(part, invS);
  dense_pass<1><<<512 * NSPLIT, 256, 0, stream>>>(hsb, (const bf16x8*)Bp, bd,
                                                  invS, out);
}

// Round 5
// 507.066 us; speedup vs baseline: 2.1455x; 2.1455x over previous
//
#include <hip/hip_runtime.h>
#include <cmath>

// Problem dims (fixed by setup_inputs)
#define B_SZ  32
#define LATD  64
#define HU    96
#define G4    384
#define T_LEN 512
#define VOC   10000
#define NROWS (B_SZ * T_LEN)        // 16384
#define NC16  625                   // 10000/16 exactly
#define NSPLIT 5
#define C16S  125                   // c16 tiles per split
#define RBLK  32                    // rows per dense block
#define PPR   (NSPLIT * 2)          // partials per row
#define PACK_BLOCKS ((NC16 * 3 * 64 + 383) / 384)   // 313
#define LSTM_GRID   (B_SZ + PACK_BLOCKS)            // 345

typedef __attribute__((ext_vector_type(8))) short bf16x8;
typedef __attribute__((ext_vector_type(4))) float f32x4;

__device__ __forceinline__ unsigned short f2bf(float x) {
  unsigned u = __float_as_uint(x);
  u += 0x7fffu + ((u >> 16) & 1u);   // RNE
  return (unsigned short)(u >> 16);
}
__device__ __forceinline__ float fsig(float x) {
  return __builtin_amdgcn_rcpf(1.f + __expf(-x));
}
__device__ __forceinline__ float ftanh(float x) {
  return 1.f - 2.f * __builtin_amdgcn_rcpf(1.f + __expf(2.f * x));
}

// ---------------- Kernel 1 (fused): LSTM recurrence + Wd packing ------------
// Blocks [0,32): LSTM, one batch element each, 6 waves.
//   Replicated-A MFMA: A-fragment = h broadcast to all 16 rows, B = U
//   fragments. Wave w owns tiles {w, 6+w, 12+w, 18+w} = gates i,f,cbar,o of
//   units u = c + 16w (c = lane&15) -> complete gate quad in-lane, no
//   cross-wave exchange. h double-buffered bf16 in LDS, 1 barrier/step.
// Blocks [32, 345): pack Wd into bf16 MFMA-B-fragment order (runs on other
//   CUs concurrently with the LSTM blocks).
__global__ __launch_bounds__(384) void lstm_fused(
    const float* __restrict__ z, const float* __restrict__ W,
    const float* __restrict__ U, const float* __restrict__ bias,
    const float* __restrict__ Wd, unsigned short* __restrict__ hsb,
    uint4* __restrict__ Bp) {
  const int tid = threadIdx.x;

  if (blockIdx.x >= B_SZ) {
    // ---- pack path: lane chunk (c16,K16,l): elem j = Wd[K16*32+(l>>4)*8+j][c16*16+(l&15)]
    const int gid = (blockIdx.x - B_SZ) * 384 + tid;
    if (gid < NC16 * 3 * 64) {
      const int l   = gid & 63;
      const int K16 = (gid >> 6) % 3;
      const int c16 = gid / 192;
      const int col = c16 * 16 + (l & 15);
      const int k0  = K16 * 32 + (l >> 4) * 8;
      unsigned wb[4];
#pragma unroll
      for (int jj = 0; jj < 4; ++jj) {
        float x0 = Wd[(size_t)(k0 + 2 * jj) * VOC + col];
        float x1 = Wd[(size_t)(k0 + 2 * jj + 1) * VOC + col];
        wb[jj] = (unsigned)f2bf(x0) | ((unsigned)f2bf(x1) << 16);
      }
      Bp[gid] = make_uint4(wb[0], wb[1], wb[2], wb[3]);
    }
    return;
  }

  // ---- LSTM path ----
  __shared__ __align__(16) unsigned short hbuf[2][HU];  // bf16 h, double-buffered
  __shared__ float z_lds[LATD];
  const int bb = blockIdx.x;
  const int l  = tid & 63, wv = tid >> 6;   // wave 0..5
  const int c  = l & 15, kg = l >> 4, k0 = kg * 8;

  if (tid < LATD)   z_lds[tid] = z[bb * LATD + tid];
  if (tid < HU / 2) ((unsigned*)hbuf[0])[tid] = 0u;

  // this lane's 4 gate columns: gate g of unit (c + 16*wv) = col 16*(6g+wv)+c
  int cols[4];
#pragma unroll
  for (int g = 0; g < 4; ++g) cols[g] = (6 * g + wv) * 16 + c;

  // U fragments (B-operand layout, verified in round 4): 48 VGPRs
  bf16x8 Ufr[4][3];
#pragma unroll
  for (int g = 0; g < 4; ++g) {
#pragma unroll
    for (int kt = 0; kt < 3; ++kt) {
      const int kb = kt * 32 + k0;
      unsigned wb[4];
#pragma unroll
      for (int jj = 0; jj < 4; ++jj) {
        float x0 = U[(size_t)(kb + 2 * jj) * G4 + cols[g]];
        float x1 = U[(size_t)(kb + 2 * jj + 1) * G4 + cols[g]];
        wb[jj] = (unsigned)f2bf(x0) | ((unsigned)f2bf(x1) << 16);
      }
      uint4 u4 = make_uint4(wb[0], wb[1], wb[2], wb[3]);
      Ufr[g][kt] = __builtin_bit_cast(bf16x8, u4);
    }
  }

  float zp[4];
#pragma unroll
  for (int g = 0; g < 4; ++g) zp[g] = bias[cols[g]];
  __syncthreads();  // z_lds + hbuf[0] ready
  for (int k = 0; k < LATD; ++k) {
    const float zk = z_lds[k];
    const float* wr = W + (size_t)k * G4;
#pragma unroll
    for (int g = 0; g < 4; ++g) zp[g] = fmaf(zk, wr[cols[g]], zp[g]);
  }

  float cst = 0.f;
  unsigned short* hrow = hsb + (size_t)bb * T_LEN * HU;
  int p = 0;
  const f32x4 zero4 = {0.f, 0.f, 0.f, 0.f};

  for (int s = 0; s < T_LEN; ++s) {
    bf16x8 afr[3];
#pragma unroll
    for (int kt = 0; kt < 3; ++kt)
      afr[kt] = *(const bf16x8*)(&hbuf[p][kt * 32 + k0]);

    float g4[4];
#pragma unroll
    for (int g = 0; g < 4; ++g) {
      f32x4 d = __builtin_amdgcn_mfma_f32_16x16x32_bf16(afr[0], Ufr[g][0], zero4, 0, 0, 0);
      d = __builtin_amdgcn_mfma_f32_16x16x32_bf16(afr[1], Ufr[g][1], d, 0, 0, 0);
      d = __builtin_amdgcn_mfma_f32_16x16x32_bf16(afr[2], Ufr[g][2], d, 0, 0, 0);
      g4[g] = d[0] + zp[g];
    }

    const float i_ = fsig(g4[0]);
    const float f_ = fsig(g4[1]);
    const float cb = ftanh(g4[2]);
    const float o_ = fsig(g4[3]);
    cst = f_ * cst + i_ * cb;
    const float h = o_ * ftanh(cst);
    const unsigned short hb = f2bf(h);
    if (kg == 0)      hbuf[p ^ 1][c + 16 * wv] = hb;       // LDS (critical path)
    else if (kg == 1) hrow[(size_t)s * HU + c + 16 * wv] = hb;  // global (off path)
    __syncthreads();
    p ^= 1;
  }
}

// ---------------- Kernels 2/4: dense GEMM passes ----------------------------
// Grid: 512 row-blocks x NSPLIT v-splits (bid: s=bid/512, rb=bid%512).
// 4 waves: r16 = wv&1 (16-row tile), cg = wv>>1 (odd/even c16 within split).
// PASS 0: partial sum(exp(logit)) -> part[row][s*2+cg].
// PASS 1: recompute logits (identical MFMA sequence) -> nontemporal out.
template <int PASS>
__global__ __launch_bounds__(256) void dense_pass(
    const unsigned short* __restrict__ hsb, const bf16x8* __restrict__ Bp,
    const float* __restrict__ bd, const float* __restrict__ invS,
    float* __restrict__ outp) {
  __shared__ __align__(16) unsigned short Al[RBLK * HU];  // 6 KB
  const int tid = threadIdx.x;
  const int l = tid & 63, wv = tid >> 6;
  const int r16 = wv & 1, cg = wv >> 1;
  const int l15 = l & 15, l4 = l >> 4;
  const int s = blockIdx.x / 512, rb = blockIdx.x % 512;
  const int R0 = rb * RBLK;

  {
    const uint4* src = (const uint4*)(hsb + (size_t)R0 * HU);
    uint4* dst = (uint4*)Al;
    for (int i = tid; i < RBLK * HU / 8; i += 256) dst[i] = src[i];
  }
  __syncthreads();

  bf16x8 afr[3];
#pragma unroll
  for (int K16 = 0; K16 < 3; ++K16)
    afr[K16] = *(const bf16x8*)(Al + (r16 * 16 + l15) * HU + K16 * 32 + l4 * 8);

  float iv[4];
  float ssum[4] = {0.f, 0.f, 0.f, 0.f};
  if (PASS == 1) {
#pragma unroll
    for (int q = 0; q < 4; ++q) iv[q] = invS[R0 + r16 * 16 + l4 * 4 + q];
  }

  const int cbase = s * C16S;
  for (int i = cg; i < C16S; i += 2) {
    const int c16 = cbase + i;
    const bf16x8* bp = Bp + (size_t)c16 * 192 + l;
    const bf16x8 b0 = bp[0], b1 = bp[64], b2 = bp[128];
    f32x4 acc = {0.f, 0.f, 0.f, 0.f};
    acc = __builtin_amdgcn_mfma_f32_16x16x32_bf16(afr[0], b0, acc, 0, 0, 0);
    acc = __builtin_amdgcn_mfma_f32_16x16x32_bf16(afr[1], b1, acc, 0, 0, 0);
    acc = __builtin_amdgcn_mfma_f32_16x16x32_bf16(afr[2], b2, acc, 0, 0, 0);
    const int col = c16 * 16 + l15;
    const float bdv = bd[col];
    if (PASS == 0) {
#pragma unroll
      for (int q = 0; q < 4; ++q) ssum[q] += __expf(acc[q] + bdv);
    } else {
#pragma unroll
      for (int q = 0; q < 4; ++q) {
        const size_t r = (size_t)(R0 + r16 * 16 + l4 * 4 + q);
        __builtin_nontemporal_store(__expf(acc[q] + bdv) * iv[q],
                                    outp + r * VOC + col);
      }
    }
  }

  if (PASS == 0) {
#pragma unroll
    for (int q = 0; q < 4; ++q) {
      float v = ssum[q];
      v += __shfl_xor(v, 1);
      v += __shfl_xor(v, 2);
      v += __shfl_xor(v, 4);
      v += __shfl_xor(v, 8);
      ssum[q] = v;
    }
    if (l15 == 0) {
#pragma unroll
      for (int q = 0; q < 4; ++q)
        outp[(size_t)(R0 + r16 * 16 + l4 * 4 + q) * PPR + s * 2 + cg] = ssum[q];
    }
  }
}

// ---------------- Kernel 3: reduce partials -> invS -------------------------
__global__ __launch_bounds__(256) void reduce_inv(const float* __restrict__ part,
                                                  float* __restrict__ invS) {
  const int r = blockIdx.x * 256 + threadIdx.x;
  if (r < NROWS) {
    float s = 0.f;
#pragma unroll
    for (int i = 0; i < PPR; ++i) s += part[(size_t)r * PPR + i];
    invS[r] = 1.f / s;
  }
}

extern "C" void kernel_launch(void* const* d_in, const int* in_sizes, int n_in,
                              void* d_out, int out_size, void* d_ws, size_t ws_size,
                              hipStream_t stream) {
  const float* z  = (const float*)d_in[0];
  const float* W  = (const float*)d_in[1];
  const float* U  = (const float*)d_in[2];
  const float* b  = (const float*)d_in[3];
  const float* Wd = (const float*)d_in[4];
  const float* bd = (const float*)d_in[5];
  float* out = (float*)d_out;

  char* ws = (char*)d_ws;
  unsigned short* hsb = (unsigned short*)ws;                 // 3,145,728 B
  uint4* Bp   = (uint4*)(ws + 3145728);                      // 1,920,000 B
  float* part = (float*)(ws + 3145728 + 1920000);            //   655,360 B
  float* invS = (float*)(ws + 3145728 + 1920000 + 655360);   //    65,536 B

  lstm_fused<<<LSTM_GRID, 384, 0, stream>>>(z, W, U, b, Wd, hsb, Bp);
  dense_pass<0><<<512 * NSPLIT, 256, 0, stream>>>(hsb, (const bf16x8*)Bp, bd,
                                                  nullptr, part);
  reduce_inv<<<(NROWS + 255) / 256, 256, 0, stream>>>(part, invS);
  dense_pass<1><<<512 * NSPLIT, 256, 0, stream>>>(hsb, (const bf16x8*)Bp, bd,
                                                  invS, out);
}